// Round 2
// baseline (538.018 us; speedup 1.0000x reference)
//
#include <hip/hip_runtime.h>
#include <hip/hip_bf16.h>

#define NN 100000
#define NP 100096            // 782 * 128, padded row count for GEMM
#define EM 1600000
#define EA 200000
#define ET (EM + EA)
#define SB 98                // scan blocks of 1024: 98*1024 >= NN

// k_count fused grid: 4 edges/thread + 8 convert uint2/thread
#define CB 1759
#define TT (CB * 256)        // 450304 threads

// ws layout (4B units):
//  norm[NN] | cnt[NN] | cursor[NN] | bsum[128] | Wb[16384] |
//  degx[8*NN] uint (per-XCD deg copies) | cntx[8*NN] uint (per-XCD cnt copies,
//  becomes per-XCD exclusive base after k_merge_wt) |
//  recSC[ET] | recEF[ET] uint2 | featsb[64*NP] | rstb[64*NP] | rank16[ET] ushort
#define OFF_NORM 0
#define OFF_CNT  (NN)
#define OFF_CUR  (2*NN)
#define OFF_BSUM (3*NN)
#define OFF_WB   (3*NN + 128)
#define OFF_DEGX (OFF_WB + 16384)
#define OFF_CNTX (OFF_DEGX + 8*NN)
#define OFF_RSC  (OFF_CNTX + 8*NN)
#define OFF_REF  (OFF_RSC + ET)
#define OFF_FB   (OFF_REF + 2*ET)
#define OFF_RB   (OFF_FB + 64*NP)
#define OFF_RANK (OFF_RB + 64*NP)

#define UNP_LO(u) __uint_as_float((u) << 16)
#define UNP_HI(u) __uint_as_float((u) & 0xFFFF0000u)

typedef __attribute__((ext_vector_type(8))) short bf16x8;
typedef __attribute__((ext_vector_type(4))) float f32x4;

static __device__ __forceinline__ unsigned pack_bf16x2(float a, float b) {
  union { __hip_bfloat162 v; unsigned u; } cv;
  cv.v = __float22bfloat162_rn(make_float2(a, b));
  return cv.u;
}

// Fused: (1) feats->bf16 conversion, (2) degree + dst histogram with per-edge
// rank. Histograms are privatized per XCD (8 copies) so the atomics can be
// workgroup-scope: sc1=0 -> the RMW executes inside the local TCC (L2) at
// cache-atomic rate instead of writing through to the memory-side coherence
// point (which floored at ~19 G atomics/s, 32 B EA write per atomic).
// Cross-kernel visibility comes from the dispatch-end L2 writeback.
__global__ __launch_bounds__(256) void k_count(
    const int* __restrict__ srcE, const int* __restrict__ dstE,
    const int* __restrict__ dstA, const float* __restrict__ feats,
    unsigned* __restrict__ degx, unsigned* __restrict__ cntx,
    unsigned short* __restrict__ rank16, uint2* __restrict__ fb2) {
  unsigned xcd;
  asm volatile("s_getreg_b32 %0, hwreg(HW_REG_XCC_ID)" : "=s"(xcd));
  xcd &= 7u;
  unsigned* degp = degx + xcd * NN;
  unsigned* cntp = cntx + xcd * NN;
  unsigned xtag = xcd << 13;

  int u = blockIdx.x * 256 + threadIdx.x;

  // feats -> packed bf16 pairs; zero the pad rows. 8 * TT >= NP*32.
#pragma unroll
  for (int k = 0; k < 8; ++k) {
    int p = u + k * TT;
    if (p < NN * 32) {
      float4 f = ((const float4*)feats)[p];
      fb2[p] = make_uint2(pack_bf16x2(f.x, f.y), pack_bf16x2(f.z, f.w));
    } else if (p < NP * 32) {
      fb2[p] = make_uint2(0u, 0u);
    }
  }

  // histogram + rank; 4 * TT >= ET
#pragma unroll
  for (int k = 0; k < 4; ++k) {
    int e = u + k * TT;
    if (e < EM) {
      __hip_atomic_fetch_add(&degp[srcE[e]], 1u, __ATOMIC_RELAXED,
                             __HIP_MEMORY_SCOPE_WORKGROUP);
      unsigned r = __hip_atomic_fetch_add(&cntp[dstE[e]], 1u, __ATOMIC_RELAXED,
                                          __HIP_MEMORY_SCOPE_WORKGROUP);
      rank16[e] = (unsigned short)(xtag | r);
    } else if (e < ET) {
      unsigned r = __hip_atomic_fetch_add(&cntp[dstA[e - EM]], 1u,
                                          __ATOMIC_RELAXED,
                                          __HIP_MEMORY_SCOPE_WORKGROUP);
      rank16[e] = (unsigned short)(xtag | r);
    }
  }
}

// Merge the 8 per-XCD copies: norm = rsqrt(sum deg), cnt = sum cntx, and
// cntx[x][i] becomes the per-XCD exclusive base (prefix over x). Also builds
// Wb bf16: Wb[j][k] = Wmsg[j][k] (k<128), Wskip[j][k-128] (k>=128).
__global__ __launch_bounds__(256) void k_merge_wt(
    const unsigned* __restrict__ degx, unsigned* __restrict__ cntx,
    unsigned* __restrict__ cnt, float* __restrict__ norm,
    const float* __restrict__ Wmsg, const float* __restrict__ Wskip,
    unsigned* __restrict__ Wb) {
  int i = blockIdx.x * 256 + threadIdx.x;
  if (i < NN) {
    unsigned d = 0;
#pragma unroll
    for (int x = 0; x < 8; ++x) d += degx[x * NN + i];
    norm[i] = d ? rsqrtf((float)d) : 0.0f;
    unsigned t = 0;
#pragma unroll
    for (int x = 0; x < 8; ++x) {
      unsigned c = cntx[x * NN + i];
      cntx[x * NN + i] = t;
      t += c;
    }
    cnt[i] = t;
  }
  if (i < 16384) {
    int j = i >> 7, kk = i & 127;   // kk = uint index within row (2 bf16)
    float a, b;
    if (kk < 64) {
      a = Wmsg[j * 128 + 2 * kk];
      b = Wmsg[j * 128 + 2 * kk + 1];
    } else {
      a = Wskip[j * 128 + 2 * kk - 128];
      b = Wskip[j * 128 + 2 * kk - 127];
    }
    Wb[j * 128 + kk] = pack_bf16x2(a, b);
  }
}

__global__ __launch_bounds__(1024) void k_scan1(const unsigned* __restrict__ cnt,
                                                int* __restrict__ bsum) {
  __shared__ int ws16[16];
  int tid = threadIdx.x, lane = tid & 63, wid = tid >> 6;
  int i = blockIdx.x * 1024 + tid;
  int v = (i < NN) ? (int)cnt[i] : 0;
#pragma unroll
  for (int s = 1; s < 64; s <<= 1) v += __shfl_xor(v, s, 64);
  if (lane == 0) ws16[wid] = v;
  __syncthreads();
  if (tid == 0) {
    int a = 0;
#pragma unroll
    for (int w = 0; w < 16; ++w) a += ws16[w];
    bsum[blockIdx.x] = a;
  }
}

__global__ __launch_bounds__(64) void k_scan2(int* __restrict__ bsum) {
  int lane = threadIdx.x;
  int v0 = (lane < SB) ? bsum[lane] : 0;
  int v1 = (64 + lane < SB) ? bsum[64 + lane] : 0;
  int x0 = v0, x1 = v1;
#pragma unroll
  for (int s = 1; s < 64; s <<= 1) {
    int y = __shfl_up(x0, s, 64); if (lane >= s) x0 += y;
  }
#pragma unroll
  for (int s = 1; s < 64; s <<= 1) {
    int y = __shfl_up(x1, s, 64); if (lane >= s) x1 += y;
  }
  int t0 = __shfl(x0, 63, 64);
  if (lane < SB) bsum[lane] = x0 - v0;
  if (64 + lane < SB) bsum[64 + lane] = t0 + x1 - v1;
}

__global__ __launch_bounds__(1024) void k_scan3(const unsigned* __restrict__ cnt,
                                                const int* __restrict__ bsum,
                                                int* __restrict__ cursor) {
  __shared__ int ws16[16];
  int tid = threadIdx.x, lane = tid & 63, wid = tid >> 6;
  int i = blockIdx.x * 1024 + tid;
  int v = (i < NN) ? (int)cnt[i] : 0;
  int x = v;
#pragma unroll
  for (int s = 1; s < 64; s <<= 1) {
    int y = __shfl_up(x, s, 64); if (lane >= s) x += y;
  }
  if (lane == 63) ws16[wid] = x;
  __syncthreads();
  if (tid == 0) {
    int a = bsum[blockIdx.x];
#pragma unroll
    for (int w = 0; w < 16; ++w) { int t = ws16[w]; ws16[w] = a; a += t; }
  }
  __syncthreads();
  if (i < NN) cursor[i] = ws16[wid] + x - v;   // exclusive start of bucket
}

// bucket by dst, atomic-free:
// slot = cursor[d] + perXCD_base[xcd][d] + rank_within_xcd
__global__ __launch_bounds__(256) void k_fill(
    const int* __restrict__ srcE, const int* __restrict__ dstE,
    const int* __restrict__ srcA, const int* __restrict__ dstA,
    const float* __restrict__ ef, const float* __restrict__ Watt,
    const float* __restrict__ batt, const float* __restrict__ norm,
    const int* __restrict__ cursor, const unsigned* __restrict__ cntx,
    const unsigned short* __restrict__ rank16,
    unsigned* __restrict__ recSC, uint2* __restrict__ recEF) {
  int e = blockIdx.x * 256 + threadIdx.x;
  if (e >= ET) return;
  int s, d;
  float att;
  float4 f;
  if (e < EM) {
    s = srcE[e]; d = dstE[e];
    f = ((const float4*)ef)[e];
    float z = f.x * Watt[0] + f.y * Watt[1] + f.z * Watt[2] + f.w * Watt[3] + batt[0];
    att = 1.0f / (1.0f + __expf(-z));
  } else {
    int ea = e - EM;
    s = srcA[ea]; d = dstA[ea];
    f = make_float4(0.f, 0.f, 0.f, 0.f);
    att = 1.0f / (1.0f + __expf(-batt[0]));
  }
  float c = att * norm[s];
  unsigned q = (unsigned)(c * 32767.0f + 0.5f);
  if (q > 32767u) q = 32767u;
  unsigned rr = rank16[e];
  int slot = cursor[d] + (int)cntx[(rr >> 13) * NN + d] + (int)(rr & 8191u);
  recSC[slot] = ((unsigned)s << 15) | q;
  recEF[slot] = make_uint2(pack_bf16x2(f.x, f.y), pack_bf16x2(f.z, f.w));
}

// Pull only: 1 wave per node, no LDS, no barriers -> 32 waves/CU for latency
// hiding. Writes rst row as packed bf16 (rstb).
__global__ __launch_bounds__(256) void k_pull(
    const float* __restrict__ feats, const unsigned* __restrict__ featsb,
    const unsigned* __restrict__ cnt, const int* __restrict__ cursor,
    const float* __restrict__ norm, const unsigned* __restrict__ recSC,
    const uint2* __restrict__ recEF,
    const float* __restrict__ Wedge, const float* __restrict__ bedge,
    unsigned* __restrict__ rstb) {
  int lane = threadIdx.x & 63, wid = threadIdx.x >> 6;
  int n = blockIdx.x * 4 + wid;
  if (n >= NP) return;
  if (n >= NN) { rstb[n * 64 + lane] = 0u; return; }

  int beg = __builtin_amdgcn_readfirstlane(cursor[n]);
  int len = __builtin_amdgcn_readfirstlane((int)cnt[n]);
  int end = beg + len;
  float2 acc = make_float2(0.f, 0.f);
  int e = beg;
  for (; e + 8 <= end; e += 8) {
    unsigned r0 = recSC[e+0], r1 = recSC[e+1], r2 = recSC[e+2], r3 = recSC[e+3];
    unsigned r4 = recSC[e+4], r5 = recSC[e+5], r6 = recSC[e+6], r7 = recSC[e+7];
    unsigned u0 = featsb[(r0 >> 15) * 64 + lane];
    unsigned u1 = featsb[(r1 >> 15) * 64 + lane];
    unsigned u2 = featsb[(r2 >> 15) * 64 + lane];
    unsigned u3 = featsb[(r3 >> 15) * 64 + lane];
    unsigned u4 = featsb[(r4 >> 15) * 64 + lane];
    unsigned u5 = featsb[(r5 >> 15) * 64 + lane];
    unsigned u6 = featsb[(r6 >> 15) * 64 + lane];
    unsigned u7 = featsb[(r7 >> 15) * 64 + lane];
    float c0 = (float)(r0 & 32767u) * (1.0f / 32767.0f);
    float c1 = (float)(r1 & 32767u) * (1.0f / 32767.0f);
    float c2 = (float)(r2 & 32767u) * (1.0f / 32767.0f);
    float c3 = (float)(r3 & 32767u) * (1.0f / 32767.0f);
    float c4 = (float)(r4 & 32767u) * (1.0f / 32767.0f);
    float c5 = (float)(r5 & 32767u) * (1.0f / 32767.0f);
    float c6 = (float)(r6 & 32767u) * (1.0f / 32767.0f);
    float c7 = (float)(r7 & 32767u) * (1.0f / 32767.0f);
    acc.x += c0 * UNP_LO(u0) + c1 * UNP_LO(u1) + c2 * UNP_LO(u2) + c3 * UNP_LO(u3)
           + c4 * UNP_LO(u4) + c5 * UNP_LO(u5) + c6 * UNP_LO(u6) + c7 * UNP_LO(u7);
    acc.y += c0 * UNP_HI(u0) + c1 * UNP_HI(u1) + c2 * UNP_HI(u2) + c3 * UNP_HI(u3)
           + c4 * UNP_HI(u4) + c5 * UNP_HI(u5) + c6 * UNP_HI(u6) + c7 * UNP_HI(u7);
  }
  for (; e < end; ++e) {
    unsigned r = recSC[e];
    unsigned u = featsb[(r >> 15) * 64 + lane];
    float c = (float)(r & 32767u) * (1.0f / 32767.0f);
    acc.x += c * UNP_LO(u);
    acc.y += c * UNP_HI(u);
  }
  // lane-parallel ef sum over the bucket, butterfly all-reduce
  float4 efa = make_float4(0.f, 0.f, 0.f, 0.f);
  for (int b = beg + lane; b < end; b += 64) {
    uint2 g = recEF[b];
    efa.x += UNP_LO(g.x); efa.y += UNP_HI(g.x);
    efa.z += UNP_LO(g.y); efa.w += UNP_HI(g.y);
  }
#pragma unroll
  for (int s = 1; s < 64; s <<= 1) {
    efa.x += __shfl_xor(efa.x, s, 64);
    efa.y += __shfl_xor(efa.y, s, 64);
    efa.z += __shfl_xor(efa.z, s, 64);
    efa.w += __shfl_xor(efa.w, s, 64);
  }
  float flen = (float)len;
  float nm = norm[n];
  float2 f = ((const float2*)feats)[n * 64 + lane];
  float4 wa = ((const float4*)Wedge)[2 * lane + 0];
  float4 wb = ((const float4*)Wedge)[2 * lane + 1];
  float2 be = ((const float2*)bedge)[lane];
  float tx = wa.x * efa.x + wa.y * efa.y + wa.z * efa.z + wa.w * efa.w;
  float ty = wb.x * efa.x + wb.y * efa.y + wb.z * efa.z + wb.w * efa.w;
  float rx = (acc.x + tx + flen * (be.x + nm * f.x)) * nm;
  float ry = (acc.y + ty + flen * (be.y + nm * f.y)) * nm;
  rstb[n * 64 + lane] = pack_bf16x2(rx, ry);
}

// MFMA GEMM: out[NN][128] = [rstb | featsb](bf16) @ Wb^T-ish + bias.
// Block 256 thr = 4 waves; block covers 128 rows; wave covers 32 rows x 128 cols.
// 16x16x32 bf16 MFMA. A: m=lane&15, k=quad*8+j. B: n=lane&15, k=quad*8+j.
// D: col=lane&15, row=quad*4+reg.
__global__ __launch_bounds__(256) void k_gemm(
    const unsigned* __restrict__ rstb, const unsigned* __restrict__ featsb,
    const unsigned* __restrict__ Wb,
    const float* __restrict__ bmsg, const float* __restrict__ bskip,
    float* __restrict__ out) {
  int lane = threadIdx.x & 63, wid = threadIdx.x >> 6;
  int quad = lane >> 4, l15 = lane & 15;
  int rowt = blockIdx.x * 128 + wid * 32;
  int m0 = rowt + l15;
  int m1 = m0 + 16;

  f32x4 acc0[8], acc1[8];
#pragma unroll
  for (int ct = 0; ct < 8; ++ct) {
    acc0[ct] = (f32x4){0.f, 0.f, 0.f, 0.f};
    acc1[ct] = (f32x4){0.f, 0.f, 0.f, 0.f};
  }

#pragma unroll
  for (int ks = 0; ks < 8; ++ks) {
    int kb = ks * 32;
    const unsigned* Xsrc = (kb < 128) ? rstb : featsb;
    int off = ((kb & 127) >> 1) + quad * 4;    // dword offset in 64-dword row
    bf16x8 a0 = *(const bf16x8*)(Xsrc + m0 * 64 + off);
    bf16x8 a1 = *(const bf16x8*)(Xsrc + m1 * 64 + off);
#pragma unroll
    for (int ct = 0; ct < 8; ++ct) {
      int j = ct * 16 + l15;
      bf16x8 b = *(const bf16x8*)(Wb + j * 128 + (kb >> 1) + quad * 4);
      acc0[ct] = __builtin_amdgcn_mfma_f32_16x16x32_bf16(a0, b, acc0[ct], 0, 0, 0);
      acc1[ct] = __builtin_amdgcn_mfma_f32_16x16x32_bf16(a1, b, acc1[ct], 0, 0, 0);
    }
  }

#pragma unroll
  for (int ct = 0; ct < 8; ++ct) {
    int col = ct * 16 + l15;
    float bia = bmsg[col] + bskip[col];
#pragma unroll
    for (int r = 0; r < 4; ++r) {
      int row0 = rowt + quad * 4 + r;
      if (row0 < NN) out[row0 * 128 + col] = acc0[ct][r] + bia;
      int row1 = row0 + 16;
      if (row1 < NN) out[row1 * 128 + col] = acc1[ct][r] + bia;
    }
  }
}

extern "C" void kernel_launch(void* const* d_in, const int* in_sizes, int n_in,
                              void* d_out, int out_size, void* d_ws, size_t ws_size,
                              hipStream_t stream) {
  const float* feats  = (const float*)d_in[0];
  const float* ef     = (const float*)d_in[1];
  const int*   srcE   = (const int*)d_in[2];
  const int*   dstE   = (const int*)d_in[3];
  const int*   srcA   = (const int*)d_in[4];
  const int*   dstA   = (const int*)d_in[5];
  const float* Wskip  = (const float*)d_in[6];
  const float* bskip  = (const float*)d_in[7];
  const float* Wmsg   = (const float*)d_in[8];
  const float* bmsg   = (const float*)d_in[9];
  const float* Wedge  = (const float*)d_in[10];
  const float* bedge  = (const float*)d_in[11];
  const float* Watt   = (const float*)d_in[12];
  const float* batt   = (const float*)d_in[13];
  float* out = (float*)d_out;
  float* ws  = (float*)d_ws;

  float*          norm   = ws + OFF_NORM;
  unsigned*       cnt    = (unsigned*)(ws + OFF_CNT);
  int*            cursor = (int*)(ws + OFF_CUR);
  int*            bsum   = (int*)(ws + OFF_BSUM);
  unsigned*       Wb     = (unsigned*)(ws + OFF_WB);
  unsigned*       degx   = (unsigned*)(ws + OFF_DEGX);
  unsigned*       cntx   = (unsigned*)(ws + OFF_CNTX);
  unsigned*       recSC  = (unsigned*)(ws + OFF_RSC);
  uint2*          recEF  = (uint2*)(ws + OFF_REF);
  unsigned*       featsb = (unsigned*)(ws + OFF_FB);
  unsigned*       rstb   = (unsigned*)(ws + OFF_RB);
  unsigned short* rank16 = (unsigned short*)(ws + OFF_RANK);

  // zero the 16 per-XCD histogram copies (degx + cntx, contiguous)
  hipMemsetAsync(ws + OFF_DEGX, 0, (size_t)(16 * NN) * sizeof(unsigned), stream);

  k_count<<<CB, 256, 0, stream>>>(srcE, dstE, dstA, feats, degx, cntx, rank16,
                                  (uint2*)featsb);
  k_merge_wt<<<(NN + 255) / 256, 256, 0, stream>>>(degx, cntx, cnt, norm,
                                                   Wmsg, Wskip, Wb);
  k_scan1<<<SB, 1024, 0, stream>>>(cnt, bsum);
  k_scan2<<<1, 64, 0, stream>>>(bsum);
  k_scan3<<<SB, 1024, 0, stream>>>(cnt, bsum, cursor);
  k_fill<<<(ET + 255) / 256, 256, 0, stream>>>(srcE, dstE, srcA, dstA, ef, Watt,
                                               batt, norm, cursor, cntx, rank16,
                                               recSC, recEF);
  k_pull<<<NP / 4, 256, 0, stream>>>(feats, featsb, cnt, cursor, norm,
                                     recSC, recEF, Wedge, bedge, rstb);
  k_gemm<<<NP / 128, 256, 0, stream>>>(rstb, featsb, Wb, bmsg, bskip, out);
}

// Round 3
// 397.339 us; speedup vs baseline: 1.3541x; 1.3541x over previous
//
#include <hip/hip_runtime.h>
#include <hip/hip_bf16.h>

#define NN 100000
#define NP 100096            // 782 * 128, padded row count for GEMM
#define EM 1600000
#define EA 200000
#define ET (EM + EA)
#define SB 98                // scan blocks of 1024: 98*1024 >= NN

#define HC 128               // chunks per histogram
#define CNT_CHUNK 14063      // 128*14063 = 1800064 >= ET
#define DEG_CHUNK 12500      // 128*12500 = EM exactly
#define PITCHW 25024         // dwords per histogram slice (= 100096 B >= NN)
#define PITCHB 100096        // bytes per slice

// ws layout (4B units):
//  norm[NN] | cnt[NN] | cursor[NN] | bsum[128] | Wb[16384] |
//  recSC[ET] | recEF[ET] uint2 | featsb[64*NP] | rstb[64*NP] | rank16[ET] ushort
// rstb region doubles as hist8 (128*PITCHW) + deg8 (128*PITCHW) before k_pull:
// 2*128*25024 = 6,406,144 dwords = 64*NP exactly. Total = 77.7 MB.
#define OFF_NORM 0
#define OFF_CNT  (NN)
#define OFF_CUR  (2*NN)
#define OFF_BSUM (3*NN)
#define OFF_WB   (3*NN + 128)
#define OFF_RSC  (OFF_WB + 16384)
#define OFF_REF  (OFF_RSC + ET)
#define OFF_FB   (OFF_REF + 2*ET)
#define OFF_RB   (OFF_FB + 64*NP)
#define OFF_RANK (OFF_RB + 64*NP)

#define UNP_LO(u) __uint_as_float((u) << 16)
#define UNP_HI(u) __uint_as_float((u) & 0xFFFF0000u)

typedef __attribute__((ext_vector_type(8))) short bf16x8;
typedef __attribute__((ext_vector_type(4))) float f32x4;

static __device__ __forceinline__ unsigned pack_bf16x2(float a, float b) {
  union { __hip_bfloat162 v; unsigned u; } cv;
  cv.v = __float22bfloat162_rn(make_float2(a, b));
  return cv.u;
}

// feats -> bf16 pairs; zero the pad rows
__global__ __launch_bounds__(256) void k_convert(
    const float* __restrict__ feats, unsigned* __restrict__ featsb) {
  int i = blockIdx.x * 256 + threadIdx.x;
  if (i >= NP * 64) return;
  if (i < NN * 64) {
    float2 f = ((const float2*)feats)[i];
    featsb[i] = pack_bf16x2(f.x, f.y);
  } else {
    featsb[i] = 0u;
  }
}

// Histogram without ANY global atomics: whole node range fits in LDS as byte
// counters (100096 B). Blocks 0..127: dst-histogram over edge chunk c, byte-
// in-word LDS atomicAdd returns the old byte = local rank (per-chunk per-node
// count is ~<=6, byte overflow impossible in practice). Blocks 128..255:
// src-histogram (deg, counts only). Each block dumps its 100 KB slice.
__global__ __launch_bounds__(1024) void k_hist(
    const int* __restrict__ srcE, const int* __restrict__ dstE,
    const int* __restrict__ dstA,
    unsigned* __restrict__ hist8w, unsigned* __restrict__ deg8w,
    unsigned short* __restrict__ rank16) {
  __shared__ unsigned h[PITCHW];
  int tid = threadIdx.x;
  for (int i = tid; i < PITCHW; i += 1024) h[i] = 0u;
  __syncthreads();
  int bid = blockIdx.x;
  if (bid < HC) {
    int c = bid;
    int e1 = c * CNT_CHUNK + CNT_CHUNK; if (e1 > ET) e1 = ET;
    for (int e = c * CNT_CHUNK + tid; e < e1; e += 1024) {
      int d = (e < EM) ? dstE[e] : dstA[e - EM];
      unsigned sh = 8u * (unsigned)(d & 3);
      unsigned old = atomicAdd(&h[d >> 2], 1u << sh);
      unsigned lr = (old >> sh) & 255u;
      rank16[e] = (unsigned short)(((unsigned)c << 9) | lr);
    }
    __syncthreads();
    unsigned* dst = hist8w + (size_t)c * PITCHW;
    for (int i = tid; i < PITCHW; i += 1024) dst[i] = h[i];
  } else {
    int c = bid - HC;
    int e1 = c * DEG_CHUNK + DEG_CHUNK;
    for (int e = c * DEG_CHUNK + tid; e < e1; e += 1024) {
      int s = srcE[e];
      atomicAdd(&h[s >> 2], 1u << (8u * (unsigned)(s & 3)));
    }
    __syncthreads();
    unsigned* dst = deg8w + (size_t)c * PITCHW;
    for (int i = tid; i < PITCHW; i += 1024) dst[i] = h[i];
  }
}

// Per node: exclusive prefix over the 128 cnt byte-slices (in place -> per-
// chunk bases), total -> cnt; sum deg slices -> norm = rsqrt. Also builds Wb.
__global__ __launch_bounds__(256) void k_merge_wt(
    unsigned char* __restrict__ hist8, const unsigned char* __restrict__ deg8,
    unsigned* __restrict__ cnt, float* __restrict__ norm,
    const float* __restrict__ Wmsg, const float* __restrict__ Wskip,
    unsigned* __restrict__ Wb) {
  int i = blockIdx.x * 256 + threadIdx.x;
  if (i < NN) {
    unsigned t = 0;
    for (int c = 0; c < HC; ++c) {
      unsigned char* p = hist8 + (size_t)c * PITCHB + i;
      unsigned b = *p;
      *p = (unsigned char)t;
      t += b;
    }
    cnt[i] = t;
    unsigned dg = 0;
    for (int c = 0; c < HC; ++c) dg += deg8[(size_t)c * PITCHB + i];
    norm[i] = dg ? rsqrtf((float)dg) : 0.0f;
  }
  if (i < 16384) {
    int j = i >> 7, kk = i & 127;   // kk = uint index within row (2 bf16)
    float a, b;
    if (kk < 64) {
      a = Wmsg[j * 128 + 2 * kk];
      b = Wmsg[j * 128 + 2 * kk + 1];
    } else {
      a = Wskip[j * 128 + 2 * kk - 128];
      b = Wskip[j * 128 + 2 * kk - 127];
    }
    Wb[j * 128 + kk] = pack_bf16x2(a, b);
  }
}

__global__ __launch_bounds__(1024) void k_scan1(const unsigned* __restrict__ cnt,
                                                int* __restrict__ bsum) {
  __shared__ int ws16[16];
  int tid = threadIdx.x, lane = tid & 63, wid = tid >> 6;
  int i = blockIdx.x * 1024 + tid;
  int v = (i < NN) ? (int)cnt[i] : 0;
#pragma unroll
  for (int s = 1; s < 64; s <<= 1) v += __shfl_xor(v, s, 64);
  if (lane == 0) ws16[wid] = v;
  __syncthreads();
  if (tid == 0) {
    int a = 0;
#pragma unroll
    for (int w = 0; w < 16; ++w) a += ws16[w];
    bsum[blockIdx.x] = a;
  }
}

__global__ __launch_bounds__(64) void k_scan2(int* __restrict__ bsum) {
  int lane = threadIdx.x;
  int v0 = (lane < SB) ? bsum[lane] : 0;
  int v1 = (64 + lane < SB) ? bsum[64 + lane] : 0;
  int x0 = v0, x1 = v1;
#pragma unroll
  for (int s = 1; s < 64; s <<= 1) {
    int y = __shfl_up(x0, s, 64); if (lane >= s) x0 += y;
  }
#pragma unroll
  for (int s = 1; s < 64; s <<= 1) {
    int y = __shfl_up(x1, s, 64); if (lane >= s) x1 += y;
  }
  int t0 = __shfl(x0, 63, 64);
  if (lane < SB) bsum[lane] = x0 - v0;
  if (64 + lane < SB) bsum[64 + lane] = t0 + x1 - v1;
}

__global__ __launch_bounds__(1024) void k_scan3(const unsigned* __restrict__ cnt,
                                                const int* __restrict__ bsum,
                                                int* __restrict__ cursor) {
  __shared__ int ws16[16];
  int tid = threadIdx.x, lane = tid & 63, wid = tid >> 6;
  int i = blockIdx.x * 1024 + tid;
  int v = (i < NN) ? (int)cnt[i] : 0;
  int x = v;
#pragma unroll
  for (int s = 1; s < 64; s <<= 1) {
    int y = __shfl_up(x, s, 64); if (lane >= s) x += y;
  }
  if (lane == 63) ws16[wid] = x;
  __syncthreads();
  if (tid == 0) {
    int a = bsum[blockIdx.x];
#pragma unroll
    for (int w = 0; w < 16; ++w) { int t = ws16[w]; ws16[w] = a; a += t; }
  }
  __syncthreads();
  if (i < NN) cursor[i] = ws16[wid] + x - v;   // exclusive start of bucket
}

// bucket by dst, atomic-free: slot = cursor[d] + chunkBase[c][d] + localrank
__global__ __launch_bounds__(256) void k_fill(
    const int* __restrict__ srcE, const int* __restrict__ dstE,
    const int* __restrict__ srcA, const int* __restrict__ dstA,
    const float* __restrict__ ef, const float* __restrict__ Watt,
    const float* __restrict__ batt, const float* __restrict__ norm,
    const int* __restrict__ cursor, const unsigned char* __restrict__ hist8,
    const unsigned short* __restrict__ rank16,
    unsigned* __restrict__ recSC, uint2* __restrict__ recEF) {
  int e = blockIdx.x * 256 + threadIdx.x;
  if (e >= ET) return;
  int s, d;
  float att;
  float4 f;
  if (e < EM) {
    s = srcE[e]; d = dstE[e];
    f = ((const float4*)ef)[e];
    float z = f.x * Watt[0] + f.y * Watt[1] + f.z * Watt[2] + f.w * Watt[3] + batt[0];
    att = 1.0f / (1.0f + __expf(-z));
  } else {
    int ea = e - EM;
    s = srcA[ea]; d = dstA[ea];
    f = make_float4(0.f, 0.f, 0.f, 0.f);
    att = 1.0f / (1.0f + __expf(-batt[0]));
  }
  float c = att * norm[s];
  unsigned q = (unsigned)(c * 32767.0f + 0.5f);
  if (q > 32767u) q = 32767u;
  unsigned rr = rank16[e];
  int slot = cursor[d] + (int)hist8[(size_t)(rr >> 9) * PITCHB + d]
           + (int)(rr & 511u);
  recSC[slot] = ((unsigned)s << 15) | q;
  recEF[slot] = make_uint2(pack_bf16x2(f.x, f.y), pack_bf16x2(f.z, f.w));
}

// Pull only: 1 wave per node, no LDS, no barriers -> 32 waves/CU for latency
// hiding. Writes rst row as packed bf16 (rstb).
__global__ __launch_bounds__(256) void k_pull(
    const float* __restrict__ feats, const unsigned* __restrict__ featsb,
    const unsigned* __restrict__ cnt, const int* __restrict__ cursor,
    const float* __restrict__ norm, const unsigned* __restrict__ recSC,
    const uint2* __restrict__ recEF,
    const float* __restrict__ Wedge, const float* __restrict__ bedge,
    unsigned* __restrict__ rstb) {
  int lane = threadIdx.x & 63, wid = threadIdx.x >> 6;
  int n = blockIdx.x * 4 + wid;
  if (n >= NP) return;
  if (n >= NN) { rstb[n * 64 + lane] = 0u; return; }

  int beg = __builtin_amdgcn_readfirstlane(cursor[n]);
  int len = __builtin_amdgcn_readfirstlane((int)cnt[n]);
  int end = beg + len;
  float2 acc = make_float2(0.f, 0.f);
  int e = beg;
  for (; e + 8 <= end; e += 8) {
    unsigned r0 = recSC[e+0], r1 = recSC[e+1], r2 = recSC[e+2], r3 = recSC[e+3];
    unsigned r4 = recSC[e+4], r5 = recSC[e+5], r6 = recSC[e+6], r7 = recSC[e+7];
    unsigned u0 = featsb[(r0 >> 15) * 64 + lane];
    unsigned u1 = featsb[(r1 >> 15) * 64 + lane];
    unsigned u2 = featsb[(r2 >> 15) * 64 + lane];
    unsigned u3 = featsb[(r3 >> 15) * 64 + lane];
    unsigned u4 = featsb[(r4 >> 15) * 64 + lane];
    unsigned u5 = featsb[(r5 >> 15) * 64 + lane];
    unsigned u6 = featsb[(r6 >> 15) * 64 + lane];
    unsigned u7 = featsb[(r7 >> 15) * 64 + lane];
    float c0 = (float)(r0 & 32767u) * (1.0f / 32767.0f);
    float c1 = (float)(r1 & 32767u) * (1.0f / 32767.0f);
    float c2 = (float)(r2 & 32767u) * (1.0f / 32767.0f);
    float c3 = (float)(r3 & 32767u) * (1.0f / 32767.0f);
    float c4 = (float)(r4 & 32767u) * (1.0f / 32767.0f);
    float c5 = (float)(r5 & 32767u) * (1.0f / 32767.0f);
    float c6 = (float)(r6 & 32767u) * (1.0f / 32767.0f);
    float c7 = (float)(r7 & 32767u) * (1.0f / 32767.0f);
    acc.x += c0 * UNP_LO(u0) + c1 * UNP_LO(u1) + c2 * UNP_LO(u2) + c3 * UNP_LO(u3)
           + c4 * UNP_LO(u4) + c5 * UNP_LO(u5) + c6 * UNP_LO(u6) + c7 * UNP_LO(u7);
    acc.y += c0 * UNP_HI(u0) + c1 * UNP_HI(u1) + c2 * UNP_HI(u2) + c3 * UNP_HI(u3)
           + c4 * UNP_HI(u4) + c5 * UNP_HI(u5) + c6 * UNP_HI(u6) + c7 * UNP_HI(u7);
  }
  for (; e < end; ++e) {
    unsigned r = recSC[e];
    unsigned u = featsb[(r >> 15) * 64 + lane];
    float c = (float)(r & 32767u) * (1.0f / 32767.0f);
    acc.x += c * UNP_LO(u);
    acc.y += c * UNP_HI(u);
  }
  // lane-parallel ef sum over the bucket, butterfly all-reduce
  float4 efa = make_float4(0.f, 0.f, 0.f, 0.f);
  for (int b = beg + lane; b < end; b += 64) {
    uint2 g = recEF[b];
    efa.x += UNP_LO(g.x); efa.y += UNP_HI(g.x);
    efa.z += UNP_LO(g.y); efa.w += UNP_HI(g.y);
  }
#pragma unroll
  for (int s = 1; s < 64; s <<= 1) {
    efa.x += __shfl_xor(efa.x, s, 64);
    efa.y += __shfl_xor(efa.y, s, 64);
    efa.z += __shfl_xor(efa.z, s, 64);
    efa.w += __shfl_xor(efa.w, s, 64);
  }
  float flen = (float)len;
  float nm = norm[n];
  float2 f = ((const float2*)feats)[n * 64 + lane];
  float4 wa = ((const float4*)Wedge)[2 * lane + 0];
  float4 wb = ((const float4*)Wedge)[2 * lane + 1];
  float2 be = ((const float2*)bedge)[lane];
  float tx = wa.x * efa.x + wa.y * efa.y + wa.z * efa.z + wa.w * efa.w;
  float ty = wb.x * efa.x + wb.y * efa.y + wb.z * efa.z + wb.w * efa.w;
  float rx = (acc.x + tx + flen * (be.x + nm * f.x)) * nm;
  float ry = (acc.y + ty + flen * (be.y + nm * f.y)) * nm;
  rstb[n * 64 + lane] = pack_bf16x2(rx, ry);
}

// MFMA GEMM: out[NN][128] = [rstb | featsb](bf16) @ Wb^T-ish + bias.
__global__ __launch_bounds__(256) void k_gemm(
    const unsigned* __restrict__ rstb, const unsigned* __restrict__ featsb,
    const unsigned* __restrict__ Wb,
    const float* __restrict__ bmsg, const float* __restrict__ bskip,
    float* __restrict__ out) {
  int lane = threadIdx.x & 63, wid = threadIdx.x >> 6;
  int quad = lane >> 4, l15 = lane & 15;
  int rowt = blockIdx.x * 128 + wid * 32;
  int m0 = rowt + l15;
  int m1 = m0 + 16;

  f32x4 acc0[8], acc1[8];
#pragma unroll
  for (int ct = 0; ct < 8; ++ct) {
    acc0[ct] = (f32x4){0.f, 0.f, 0.f, 0.f};
    acc1[ct] = (f32x4){0.f, 0.f, 0.f, 0.f};
  }

#pragma unroll
  for (int ks = 0; ks < 8; ++ks) {
    int kb = ks * 32;
    const unsigned* Xsrc = (kb < 128) ? rstb : featsb;
    int off = ((kb & 127) >> 1) + quad * 4;    // dword offset in 64-dword row
    bf16x8 a0 = *(const bf16x8*)(Xsrc + m0 * 64 + off);
    bf16x8 a1 = *(const bf16x8*)(Xsrc + m1 * 64 + off);
#pragma unroll
    for (int ct = 0; ct < 8; ++ct) {
      int j = ct * 16 + l15;
      bf16x8 b = *(const bf16x8*)(Wb + j * 128 + (kb >> 1) + quad * 4);
      acc0[ct] = __builtin_amdgcn_mfma_f32_16x16x32_bf16(a0, b, acc0[ct], 0, 0, 0);
      acc1[ct] = __builtin_amdgcn_mfma_f32_16x16x32_bf16(a1, b, acc1[ct], 0, 0, 0);
    }
  }

#pragma unroll
  for (int ct = 0; ct < 8; ++ct) {
    int col = ct * 16 + l15;
    float bia = bmsg[col] + bskip[col];
#pragma unroll
    for (int r = 0; r < 4; ++r) {
      int row0 = rowt + quad * 4 + r;
      if (row0 < NN) out[row0 * 128 + col] = acc0[ct][r] + bia;
      int row1 = row0 + 16;
      if (row1 < NN) out[row1 * 128 + col] = acc1[ct][r] + bia;
    }
  }
}

extern "C" void kernel_launch(void* const* d_in, const int* in_sizes, int n_in,
                              void* d_out, int out_size, void* d_ws, size_t ws_size,
                              hipStream_t stream) {
  const float* feats  = (const float*)d_in[0];
  const float* ef     = (const float*)d_in[1];
  const int*   srcE   = (const int*)d_in[2];
  const int*   dstE   = (const int*)d_in[3];
  const int*   srcA   = (const int*)d_in[4];
  const int*   dstA   = (const int*)d_in[5];
  const float* Wskip  = (const float*)d_in[6];
  const float* bskip  = (const float*)d_in[7];
  const float* Wmsg   = (const float*)d_in[8];
  const float* bmsg   = (const float*)d_in[9];
  const float* Wedge  = (const float*)d_in[10];
  const float* bedge  = (const float*)d_in[11];
  const float* Watt   = (const float*)d_in[12];
  const float* batt   = (const float*)d_in[13];
  float* out = (float*)d_out;
  float* ws  = (float*)d_ws;

  float*          norm   = ws + OFF_NORM;
  unsigned*       cnt    = (unsigned*)(ws + OFF_CNT);
  int*            cursor = (int*)(ws + OFF_CUR);
  int*            bsum   = (int*)(ws + OFF_BSUM);
  unsigned*       Wb     = (unsigned*)(ws + OFF_WB);
  unsigned*       recSC  = (unsigned*)(ws + OFF_RSC);
  uint2*          recEF  = (uint2*)(ws + OFF_REF);
  unsigned*       featsb = (unsigned*)(ws + OFF_FB);
  unsigned*       rstb   = (unsigned*)(ws + OFF_RB);
  unsigned short* rank16 = (unsigned short*)(ws + OFF_RANK);

  // histogram slices overlay the rstb region (dead until k_pull rewrites it)
  unsigned*       hist8w = rstb;
  unsigned*       deg8w  = rstb + (size_t)HC * PITCHW;
  unsigned char*  hist8b = (unsigned char*)hist8w;
  unsigned char*  deg8b  = (unsigned char*)deg8w;

  k_convert<<<(NP * 64 + 255) / 256, 256, 0, stream>>>(feats, featsb);
  k_hist<<<2 * HC, 1024, 0, stream>>>(srcE, dstE, dstA, hist8w, deg8w, rank16);
  k_merge_wt<<<(NN + 255) / 256, 256, 0, stream>>>(hist8b, deg8b, cnt, norm,
                                                   Wmsg, Wskip, Wb);
  k_scan1<<<SB, 1024, 0, stream>>>(cnt, bsum);
  k_scan2<<<1, 64, 0, stream>>>(bsum);
  k_scan3<<<SB, 1024, 0, stream>>>(cnt, bsum, cursor);
  k_fill<<<(ET + 255) / 256, 256, 0, stream>>>(srcE, dstE, srcA, dstA, ef, Watt,
                                               batt, norm, cursor, hist8b,
                                               rank16, recSC, recEF);
  k_pull<<<NP / 4, 256, 0, stream>>>(feats, featsb, cnt, cursor, norm,
                                     recSC, recEF, Wedge, bedge, rstb);
  k_gemm<<<NP / 128, 256, 0, stream>>>(rstb, featsb, Wb, bmsg, bskip, out);
}

// Round 4
// 374.365 us; speedup vs baseline: 1.4371x; 1.0614x over previous
//
#include <hip/hip_runtime.h>
#include <hip/hip_bf16.h>

#define NN 100000
#define NP 100096            // 782 * 128, padded row count for GEMM
#define EM 1600000
#define EA 200000
#define ET (EM + EA)
#define SB 98                // scan blocks of 1024: 98*1024 >= NN

#define HC 128               // chunks per histogram
#define CNT_CHUNK 14063      // 128*14063 = 1800064 >= ET
#define DEG_CHUNK 12500      // 128*12500 = EM exactly
#define PITCHW 25024         // dwords per histogram slice (= 100096 B >= NN)
#define PITCHB 100096        // bytes per slice

// ws layout (4B units):
//  norm[NN] | cnt[NN] | cursor[NN] | bsum[128] | Wb[16384] |
//  rec[ET] uint4 | featsb[64*NP] | rstb[64*NP] | rank16[ET] ushort
// rstb region doubles as hist8 (128*PITCHW) + deg8 (128*PITCHW) before k_pull.
// total = 21,228,800 dwords = 84.9 MB (84.1 MB layout passed in round 2).
#define OFF_NORM 0
#define OFF_CNT  (NN)
#define OFF_CUR  (2*NN)
#define OFF_BSUM (3*NN)
#define OFF_WB   (3*NN + 128)
#define OFF_REC  (OFF_WB + 16384)    // 16B-aligned: 316512 % 4 == 0
#define OFF_FB   (OFF_REC + 4*ET)
#define OFF_RB   (OFF_FB + 64*NP)
#define OFF_RANK (OFF_RB + 64*NP)

#define UNP_LO(u) __uint_as_float((u) << 16)
#define UNP_HI(u) __uint_as_float((u) & 0xFFFF0000u)

typedef __attribute__((ext_vector_type(8))) short bf16x8;
typedef __attribute__((ext_vector_type(4))) float f32x4;

static __device__ __forceinline__ unsigned pack_bf16x2(float a, float b) {
  union { __hip_bfloat162 v; unsigned u; } cv;
  cv.v = __float22bfloat162_rn(make_float2(a, b));
  return cv.u;
}

// Histogram without global atomics (LDS byte counters) + fused feats->bf16
// convert (streams on the otherwise latency-idle resident blocks).
// Blocks 0..127: dst-histogram over edge chunk c; byte-in-word LDS atomicAdd
// old value = local rank. Blocks 128..255: src-histogram (deg). Each block
// dumps its 100 KB slice.
__global__ __launch_bounds__(1024) void k_hist(
    const int* __restrict__ srcE, const int* __restrict__ dstE,
    const int* __restrict__ dstA, const float* __restrict__ feats,
    unsigned* __restrict__ featsb,
    unsigned* __restrict__ hist8w, unsigned* __restrict__ deg8w,
    unsigned short* __restrict__ rank16) {
  __shared__ unsigned h[PITCHW];
  int tid = threadIdx.x;
  int bid = blockIdx.x;

  // fused convert: grid-stride over NP*64 dwords (2*HC*1024 = 262144 threads)
  for (int i = bid * 1024 + tid; i < NP * 64; i += 2 * HC * 1024) {
    if (i < NN * 64) {
      float2 f = ((const float2*)feats)[i];
      featsb[i] = pack_bf16x2(f.x, f.y);
    } else {
      featsb[i] = 0u;
    }
  }

  for (int i = tid; i < PITCHW; i += 1024) h[i] = 0u;
  __syncthreads();
  if (bid < HC) {
    int c = bid;
    int e1 = c * CNT_CHUNK + CNT_CHUNK; if (e1 > ET) e1 = ET;
    for (int e = c * CNT_CHUNK + tid; e < e1; e += 1024) {
      int d = (e < EM) ? dstE[e] : dstA[e - EM];
      unsigned sh = 8u * (unsigned)(d & 3);
      unsigned old = atomicAdd(&h[d >> 2], 1u << sh);
      unsigned lr = (old >> sh) & 255u;
      rank16[e] = (unsigned short)(((unsigned)c << 9) | lr);
    }
    __syncthreads();
    unsigned* dst = hist8w + (size_t)c * PITCHW;
    for (int i = tid; i < PITCHW; i += 1024) dst[i] = h[i];
  } else {
    int c = bid - HC;
    int e1 = c * DEG_CHUNK + DEG_CHUNK;
    for (int e = c * DEG_CHUNK + tid; e < e1; e += 1024) {
      int s = srcE[e];
      atomicAdd(&h[s >> 2], 1u << (8u * (unsigned)(s & 3)));
    }
    __syncthreads();
    unsigned* dst = deg8w + (size_t)c * PITCHW;
    for (int i = tid; i < PITCHW; i += 1024) dst[i] = h[i];
  }
}

// Per node: exclusive prefix over the 128 cnt byte-slices (in place -> per-
// chunk bases), total -> cnt; sum deg slices -> norm = rsqrt. Also builds Wb.
__global__ __launch_bounds__(256) void k_merge_wt(
    unsigned char* __restrict__ hist8, const unsigned char* __restrict__ deg8,
    unsigned* __restrict__ cnt, float* __restrict__ norm,
    const float* __restrict__ Wmsg, const float* __restrict__ Wskip,
    unsigned* __restrict__ Wb) {
  int i = blockIdx.x * 256 + threadIdx.x;
  if (i < NN) {
    unsigned t = 0;
    for (int c = 0; c < HC; ++c) {
      unsigned char* p = hist8 + (size_t)c * PITCHB + i;
      unsigned b = *p;
      *p = (unsigned char)t;
      t += b;
    }
    cnt[i] = t;
    unsigned dg = 0;
    for (int c = 0; c < HC; ++c) dg += deg8[(size_t)c * PITCHB + i];
    norm[i] = dg ? rsqrtf((float)dg) : 0.0f;
  }
  if (i < 16384) {
    int j = i >> 7, kk = i & 127;   // kk = uint index within row (2 bf16)
    float a, b;
    if (kk < 64) {
      a = Wmsg[j * 128 + 2 * kk];
      b = Wmsg[j * 128 + 2 * kk + 1];
    } else {
      a = Wskip[j * 128 + 2 * kk - 128];
      b = Wskip[j * 128 + 2 * kk - 127];
    }
    Wb[j * 128 + kk] = pack_bf16x2(a, b);
  }
}

__global__ __launch_bounds__(1024) void k_scan1(const unsigned* __restrict__ cnt,
                                                int* __restrict__ bsum) {
  __shared__ int ws16[16];
  int tid = threadIdx.x, lane = tid & 63, wid = tid >> 6;
  int i = blockIdx.x * 1024 + tid;
  int v = (i < NN) ? (int)cnt[i] : 0;
#pragma unroll
  for (int s = 1; s < 64; s <<= 1) v += __shfl_xor(v, s, 64);
  if (lane == 0) ws16[wid] = v;
  __syncthreads();
  if (tid == 0) {
    int a = 0;
#pragma unroll
    for (int w = 0; w < 16; ++w) a += ws16[w];
    bsum[blockIdx.x] = a;
  }
}

__global__ __launch_bounds__(64) void k_scan2(int* __restrict__ bsum) {
  int lane = threadIdx.x;
  int v0 = (lane < SB) ? bsum[lane] : 0;
  int v1 = (64 + lane < SB) ? bsum[64 + lane] : 0;
  int x0 = v0, x1 = v1;
#pragma unroll
  for (int s = 1; s < 64; s <<= 1) {
    int y = __shfl_up(x0, s, 64); if (lane >= s) x0 += y;
  }
#pragma unroll
  for (int s = 1; s < 64; s <<= 1) {
    int y = __shfl_up(x1, s, 64); if (lane >= s) x1 += y;
  }
  int t0 = __shfl(x0, 63, 64);
  if (lane < SB) bsum[lane] = x0 - v0;
  if (64 + lane < SB) bsum[64 + lane] = t0 + x1 - v1;
}

__global__ __launch_bounds__(1024) void k_scan3(const unsigned* __restrict__ cnt,
                                                const int* __restrict__ bsum,
                                                int* __restrict__ cursor) {
  __shared__ int ws16[16];
  int tid = threadIdx.x, lane = tid & 63, wid = tid >> 6;
  int i = blockIdx.x * 1024 + tid;
  int v = (i < NN) ? (int)cnt[i] : 0;
  int x = v;
#pragma unroll
  for (int s = 1; s < 64; s <<= 1) {
    int y = __shfl_up(x, s, 64); if (lane >= s) x += y;
  }
  if (lane == 63) ws16[wid] = x;
  __syncthreads();
  if (tid == 0) {
    int a = bsum[blockIdx.x];
#pragma unroll
    for (int w = 0; w < 16; ++w) { int t = ws16[w]; ws16[w] = a; a += t; }
  }
  __syncthreads();
  if (i < NN) cursor[i] = ws16[wid] + x - v;   // exclusive start of bucket
}

// bucket by dst, atomic-free: slot = cursor[d] + chunkBase[c][d] + localrank.
// ONE 16 B scattered write per edge (was two: 4 B + 8 B -> 2x 32 B sectors).
// rec = {src, fp32 coef = att*norm[src], ef01 bf16x2, ef23 bf16x2}
__global__ __launch_bounds__(256) void k_fill(
    const int* __restrict__ srcE, const int* __restrict__ dstE,
    const int* __restrict__ srcA, const int* __restrict__ dstA,
    const float* __restrict__ ef, const float* __restrict__ Watt,
    const float* __restrict__ batt, const float* __restrict__ norm,
    const int* __restrict__ cursor, const unsigned char* __restrict__ hist8,
    const unsigned short* __restrict__ rank16,
    uint4* __restrict__ rec) {
  int e = blockIdx.x * 256 + threadIdx.x;
  if (e >= ET) return;
  int s, d;
  float att;
  float4 f;
  if (e < EM) {
    s = srcE[e]; d = dstE[e];
    f = ((const float4*)ef)[e];
    float z = f.x * Watt[0] + f.y * Watt[1] + f.z * Watt[2] + f.w * Watt[3] + batt[0];
    att = 1.0f / (1.0f + __expf(-z));
  } else {
    int ea = e - EM;
    s = srcA[ea]; d = dstA[ea];
    f = make_float4(0.f, 0.f, 0.f, 0.f);
    att = 1.0f / (1.0f + __expf(-batt[0]));
  }
  float c = att * norm[s];
  unsigned rr = rank16[e];
  int slot = cursor[d] + (int)hist8[(size_t)(rr >> 9) * PITCHB + d]
           + (int)(rr & 511u);
  rec[slot] = make_uint4((unsigned)s, __float_as_uint(c),
                         pack_bf16x2(f.x, f.y), pack_bf16x2(f.z, f.w));
}

// Pull only: 1 wave per node, no LDS, no barriers. Records are broadcast-read
// (all lanes same address); every lane redundantly accumulates the ef-sum in
// register (VALU is idle), removing the old strided pass + butterfly reduce.
__global__ __launch_bounds__(256) void k_pull(
    const float* __restrict__ feats, const unsigned* __restrict__ featsb,
    const unsigned* __restrict__ cnt, const int* __restrict__ cursor,
    const float* __restrict__ norm, const uint4* __restrict__ rec,
    const float* __restrict__ Wedge, const float* __restrict__ bedge,
    unsigned* __restrict__ rstb) {
  int lane = threadIdx.x & 63, wid = threadIdx.x >> 6;
  int n = blockIdx.x * 4 + wid;
  if (n >= NP) return;
  if (n >= NN) { rstb[n * 64 + lane] = 0u; return; }

  int beg = __builtin_amdgcn_readfirstlane(cursor[n]);
  int len = __builtin_amdgcn_readfirstlane((int)cnt[n]);
  int end = beg + len;
  float2 acc = make_float2(0.f, 0.f);
  float4 efa = make_float4(0.f, 0.f, 0.f, 0.f);
  int e = beg;
  for (; e + 8 <= end; e += 8) {
    uint4 r0 = rec[e+0], r1 = rec[e+1], r2 = rec[e+2], r3 = rec[e+3];
    uint4 r4 = rec[e+4], r5 = rec[e+5], r6 = rec[e+6], r7 = rec[e+7];
    unsigned u0 = featsb[r0.x * 64 + lane];
    unsigned u1 = featsb[r1.x * 64 + lane];
    unsigned u2 = featsb[r2.x * 64 + lane];
    unsigned u3 = featsb[r3.x * 64 + lane];
    unsigned u4 = featsb[r4.x * 64 + lane];
    unsigned u5 = featsb[r5.x * 64 + lane];
    unsigned u6 = featsb[r6.x * 64 + lane];
    unsigned u7 = featsb[r7.x * 64 + lane];
    float c0 = __uint_as_float(r0.y), c1 = __uint_as_float(r1.y);
    float c2 = __uint_as_float(r2.y), c3 = __uint_as_float(r3.y);
    float c4 = __uint_as_float(r4.y), c5 = __uint_as_float(r5.y);
    float c6 = __uint_as_float(r6.y), c7 = __uint_as_float(r7.y);
    acc.x += c0 * UNP_LO(u0) + c1 * UNP_LO(u1) + c2 * UNP_LO(u2) + c3 * UNP_LO(u3)
           + c4 * UNP_LO(u4) + c5 * UNP_LO(u5) + c6 * UNP_LO(u6) + c7 * UNP_LO(u7);
    acc.y += c0 * UNP_HI(u0) + c1 * UNP_HI(u1) + c2 * UNP_HI(u2) + c3 * UNP_HI(u3)
           + c4 * UNP_HI(u4) + c5 * UNP_HI(u5) + c6 * UNP_HI(u6) + c7 * UNP_HI(u7);
    efa.x += UNP_LO(r0.z) + UNP_LO(r1.z) + UNP_LO(r2.z) + UNP_LO(r3.z)
           + UNP_LO(r4.z) + UNP_LO(r5.z) + UNP_LO(r6.z) + UNP_LO(r7.z);
    efa.y += UNP_HI(r0.z) + UNP_HI(r1.z) + UNP_HI(r2.z) + UNP_HI(r3.z)
           + UNP_HI(r4.z) + UNP_HI(r5.z) + UNP_HI(r6.z) + UNP_HI(r7.z);
    efa.z += UNP_LO(r0.w) + UNP_LO(r1.w) + UNP_LO(r2.w) + UNP_LO(r3.w)
           + UNP_LO(r4.w) + UNP_LO(r5.w) + UNP_LO(r6.w) + UNP_LO(r7.w);
    efa.w += UNP_HI(r0.w) + UNP_HI(r1.w) + UNP_HI(r2.w) + UNP_HI(r3.w)
           + UNP_HI(r4.w) + UNP_HI(r5.w) + UNP_HI(r6.w) + UNP_HI(r7.w);
  }
  for (; e < end; ++e) {
    uint4 r = rec[e];
    unsigned u = featsb[r.x * 64 + lane];
    float c = __uint_as_float(r.y);
    acc.x += c * UNP_LO(u);
    acc.y += c * UNP_HI(u);
    efa.x += UNP_LO(r.z); efa.y += UNP_HI(r.z);
    efa.z += UNP_LO(r.w); efa.w += UNP_HI(r.w);
  }
  float flen = (float)len;
  float nm = norm[n];
  float2 f = ((const float2*)feats)[n * 64 + lane];
  float4 wa = ((const float4*)Wedge)[2 * lane + 0];
  float4 wb = ((const float4*)Wedge)[2 * lane + 1];
  float2 be = ((const float2*)bedge)[lane];
  float tx = wa.x * efa.x + wa.y * efa.y + wa.z * efa.z + wa.w * efa.w;
  float ty = wb.x * efa.x + wb.y * efa.y + wb.z * efa.z + wb.w * efa.w;
  float rx = (acc.x + tx + flen * (be.x + nm * f.x)) * nm;
  float ry = (acc.y + ty + flen * (be.y + nm * f.y)) * nm;
  rstb[n * 64 + lane] = pack_bf16x2(rx, ry);
}

// MFMA GEMM: out[NN][128] = [rstb | featsb](bf16) @ Wb^T-ish + bias.
__global__ __launch_bounds__(256) void k_gemm(
    const unsigned* __restrict__ rstb, const unsigned* __restrict__ featsb,
    const unsigned* __restrict__ Wb,
    const float* __restrict__ bmsg, const float* __restrict__ bskip,
    float* __restrict__ out) {
  int lane = threadIdx.x & 63, wid = threadIdx.x >> 6;
  int quad = lane >> 4, l15 = lane & 15;
  int rowt = blockIdx.x * 128 + wid * 32;
  int m0 = rowt + l15;
  int m1 = m0 + 16;

  f32x4 acc0[8], acc1[8];
#pragma unroll
  for (int ct = 0; ct < 8; ++ct) {
    acc0[ct] = (f32x4){0.f, 0.f, 0.f, 0.f};
    acc1[ct] = (f32x4){0.f, 0.f, 0.f, 0.f};
  }

#pragma unroll
  for (int ks = 0; ks < 8; ++ks) {
    int kb = ks * 32;
    const unsigned* Xsrc = (kb < 128) ? rstb : featsb;
    int off = ((kb & 127) >> 1) + quad * 4;    // dword offset in 64-dword row
    bf16x8 a0 = *(const bf16x8*)(Xsrc + m0 * 64 + off);
    bf16x8 a1 = *(const bf16x8*)(Xsrc + m1 * 64 + off);
#pragma unroll
    for (int ct = 0; ct < 8; ++ct) {
      int j = ct * 16 + l15;
      bf16x8 b = *(const bf16x8*)(Wb + j * 128 + (kb >> 1) + quad * 4);
      acc0[ct] = __builtin_amdgcn_mfma_f32_16x16x32_bf16(a0, b, acc0[ct], 0, 0, 0);
      acc1[ct] = __builtin_amdgcn_mfma_f32_16x16x32_bf16(a1, b, acc1[ct], 0, 0, 0);
    }
  }

#pragma unroll
  for (int ct = 0; ct < 8; ++ct) {
    int col = ct * 16 + l15;
    float bia = bmsg[col] + bskip[col];
#pragma unroll
    for (int r = 0; r < 4; ++r) {
      int row0 = rowt + quad * 4 + r;
      if (row0 < NN) out[row0 * 128 + col] = acc0[ct][r] + bia;
      int row1 = row0 + 16;
      if (row1 < NN) out[row1 * 128 + col] = acc1[ct][r] + bia;
    }
  }
}

extern "C" void kernel_launch(void* const* d_in, const int* in_sizes, int n_in,
                              void* d_out, int out_size, void* d_ws, size_t ws_size,
                              hipStream_t stream) {
  const float* feats  = (const float*)d_in[0];
  const float* ef     = (const float*)d_in[1];
  const int*   srcE   = (const int*)d_in[2];
  const int*   dstE   = (const int*)d_in[3];
  const int*   srcA   = (const int*)d_in[4];
  const int*   dstA   = (const int*)d_in[5];
  const float* Wskip  = (const float*)d_in[6];
  const float* bskip  = (const float*)d_in[7];
  const float* Wmsg   = (const float*)d_in[8];
  const float* bmsg   = (const float*)d_in[9];
  const float* Wedge  = (const float*)d_in[10];
  const float* bedge  = (const float*)d_in[11];
  const float* Watt   = (const float*)d_in[12];
  const float* batt   = (const float*)d_in[13];
  float* out = (float*)d_out;
  float* ws  = (float*)d_ws;

  float*          norm   = ws + OFF_NORM;
  unsigned*       cnt    = (unsigned*)(ws + OFF_CNT);
  int*            cursor = (int*)(ws + OFF_CUR);
  int*            bsum   = (int*)(ws + OFF_BSUM);
  unsigned*       Wb     = (unsigned*)(ws + OFF_WB);
  uint4*          rec    = (uint4*)(ws + OFF_REC);
  unsigned*       featsb = (unsigned*)(ws + OFF_FB);
  unsigned*       rstb   = (unsigned*)(ws + OFF_RB);
  unsigned short* rank16 = (unsigned short*)(ws + OFF_RANK);

  // histogram slices overlay the rstb region (dead until k_pull rewrites it)
  unsigned*       hist8w = rstb;
  unsigned*       deg8w  = rstb + (size_t)HC * PITCHW;
  unsigned char*  hist8b = (unsigned char*)hist8w;
  unsigned char*  deg8b  = (unsigned char*)deg8w;

  k_hist<<<2 * HC, 1024, 0, stream>>>(srcE, dstE, dstA, feats, featsb,
                                      hist8w, deg8w, rank16);
  k_merge_wt<<<(NN + 255) / 256, 256, 0, stream>>>(hist8b, deg8b, cnt, norm,
                                                   Wmsg, Wskip, Wb);
  k_scan1<<<SB, 1024, 0, stream>>>(cnt, bsum);
  k_scan2<<<1, 64, 0, stream>>>(bsum);
  k_scan3<<<SB, 1024, 0, stream>>>(cnt, bsum, cursor);
  k_fill<<<(ET + 255) / 256, 256, 0, stream>>>(srcE, dstE, srcA, dstA, ef, Watt,
                                               batt, norm, cursor, hist8b,
                                               rank16, rec);
  k_pull<<<NP / 4, 256, 0, stream>>>(feats, featsb, cnt, cursor, norm,
                                     rec, Wedge, bedge, rstb);
  k_gemm<<<NP / 128, 256, 0, stream>>>(rstb, featsb, Wb, bmsg, bskip, out);
}